// Round 4
// baseline (389.369 us; speedup 1.0000x reference)
//
#include <hip/hip_runtime.h>

// Problem constants
#define B_     16384
#define TD     512     // T*D
#define HID    128
#define LAT    512     // N_TOKENS*CODE_DIM
#define NCODES 512
#define CDIM   64
#define NTOK   8
#define EPS    1e-5f
#define MARGIN 0.02f   // ~10x worst-case approx-distance error; rescue if gap smaller

typedef unsigned short u16;
typedef unsigned int   u32;
typedef short bf16x8 __attribute__((ext_vector_type(8)));   // 8 bf16 = 4 VGPR (MFMA A/B frag)
typedef float f32x4  __attribute__((ext_vector_type(4)));   // MFMA C/D frag

__device__ __forceinline__ u16 bf16_rn(float f){
    u32 u = __float_as_uint(f);
    return (u16)((u + 0x7fffu + ((u >> 16) & 1u)) >> 16);   // round-nearest-even
}
__device__ __forceinline__ float bf16_f(u16 h){ return __uint_as_float(((u32)h) << 16); }
__device__ __forceinline__ void split2(float f, u16& hi, u16& lo){
    hi = bf16_rn(f);
    lo = bf16_rn(f - bf16_f(hi));     // residual: |a - hi - lo| <= ~2^-18 |a|
}
#define MFMA16(a,b,c) __builtin_amdgcn_mfma_f32_16x16x32_bf16((a),(b),(c),0,0,0)

// ---------------------------------------------------------------------------
// Prep: c2[c] = ||codebook[c]||^2 (fp32 exact)
// ---------------------------------------------------------------------------
__global__ void c2_kernel(const float* __restrict__ cb, float* __restrict__ c2) {
    int c = blockIdx.x;
    int d = threadIdx.x;            // 64 threads = 1 wave
    float v = cb[c * CDIM + d];
    float s = v * v;
#pragma unroll
    for (int m = 32; m >= 1; m >>= 1) s += __shfl_xor(s, m, 64);
    if (d == 0) c2[c] = s;
}

// ---------------------------------------------------------------------------
// Prep: transpose+split W[K][N] -> hi/lo planes [N][K] (bf16)
// ---------------------------------------------------------------------------
__global__ void tsplit_kernel(const float* __restrict__ W, u16* __restrict__ hi,
                              u16* __restrict__ lo, int N, int kshift){
    int id = blockIdx.x * 256 + threadIdx.x;    // over N*K output elems
    int K = 1 << kshift;
    int n = id >> kshift, k = id & (K - 1);
    u16 h, l2; split2(W[(size_t)k * N + n], h, l2);
    hi[id] = h; lo[id] = l2;
}
// Prep: split codebook [512][64] (no transpose)
__global__ void csplit_kernel(const float* __restrict__ C, u16* __restrict__ hi,
                              u16* __restrict__ lo){
    int id = blockIdx.x * 256 + threadIdx.x;
    u16 h, l2; split2(C[id], h, l2);
    hi[id] = h; lo[id] = l2;
}

// ---------------------------------------------------------------------------
// Prep: P[c][t][j] = sum_k cb[c][k] * dec_w1[t*64+k][j]   (fp32 exact-class)
// Replaces decoder GEMM1: h = relu(b1 + sum_t P[idx_t][t][:]).
// ---------------------------------------------------------------------------
__global__ void pprep_kernel(const float* __restrict__ cb, const float* __restrict__ dw1,
                             float* __restrict__ P){
    int c = blockIdx.x, t = blockIdx.y, j = threadIdx.x;
    const float* wp = dw1 + (size_t)t * 64 * HID + j;
    const float* cp = cb + (size_t)c * CDIM;
    float acc = 0.f;
#pragma unroll
    for (int k = 0; k < 64; ++k) acc = fmaf(cp[k], wp[(size_t)k * HID], acc);
    P[((size_t)c * 8 + t) * HID + j] = acc;
}

// ---------------------------------------------------------------------------
// ENCODER PATH (fp32 reference numerics class): baseline VALU fp32 tiled GEMM.
// ZP adds an epilogue that ALSO writes z as bf16 hi/lo planes [token][64]
// (z values themselves unchanged — planes only feed VQ approx scoring).
// ---------------------------------------------------------------------------
template<bool RELU, bool LN, bool ZP>
__launch_bounds__(256)
__global__ void gemm_kernel(const float* __restrict__ A, const float* __restrict__ W,
                            const float* __restrict__ bias,
                            float* __restrict__ C,
                            u16* __restrict__ zph, u16* __restrict__ zpl,
                            int M, int N, int K) {
    constexpr int BM = 64, BN = 64, BK = 32;
    __shared__ float As[BK][BM + 4];   // transposed: As[k][m]
    __shared__ float Ws[BK][BN + 4];

    const int tid = threadIdx.x;
    const int tx  = tid & 15;          // 0..15 (cols)
    const int ty  = tid >> 4;          // 0..15 (rows)
    const int m0  = blockIdx.x * BM;
    const int n0  = blockIdx.y * BN;

    float acc[4][4] = {};

    for (int k0 = 0; k0 < K; k0 += BK) {
        {
            int r  = tid >> 3;               // 0..31
            int c4 = (tid & 7) * 4;          // 0..28
#pragma unroll
            for (int h = 0; h < 2; ++h) {
                int rr = r + h * 32;
                float4 v = *(const float4*)&A[(size_t)(m0 + rr) * K + k0 + c4];
                As[c4 + 0][rr] = v.x; As[c4 + 1][rr] = v.y;
                As[c4 + 2][rr] = v.z; As[c4 + 3][rr] = v.w;
            }
        }
        {
            int r  = tid >> 4;               // 0..15
            int c4 = (tid & 15) * 4;         // 0..60
#pragma unroll
            for (int h = 0; h < 2; ++h) {
                int rr = r + h * 16;
                float4 v = *(const float4*)&W[(size_t)(k0 + rr) * N + n0 + c4];
                *(float4*)&Ws[rr][c4] = v;
            }
        }
        __syncthreads();

#pragma unroll
        for (int kk = 0; kk < BK; ++kk) {
            float4 a = *(const float4*)&As[kk][ty * 4];
            float4 b = *(const float4*)&Ws[kk][tx * 4];
            float av[4] = {a.x, a.y, a.z, a.w};
            float bv[4] = {b.x, b.y, b.z, b.w};
#pragma unroll
            for (int i = 0; i < 4; ++i)
#pragma unroll
                for (int j = 0; j < 4; ++j)
                    acc[i][j] = fmaf(av[i], bv[j], acc[i][j]);
        }
        __syncthreads();
    }

    float bv[4];
#pragma unroll
    for (int j = 0; j < 4; ++j) bv[j] = bias[n0 + tx * 4 + j];

#pragma unroll
    for (int i = 0; i < 4; ++i) {
        float c[4];
#pragma unroll
        for (int j = 0; j < 4; ++j) {
            c[j] = acc[i][j] + bv[j];
            if (RELU) c[j] = fmaxf(c[j], 0.0f);
        }
        if (LN) {
            float s  = c[0] + c[1] + c[2] + c[3];
            float ss = c[0]*c[0] + c[1]*c[1] + c[2]*c[2] + c[3]*c[3];
#pragma unroll
            for (int m = 1; m <= 8; m <<= 1) {
                s  += __shfl_xor(s,  m, 64);
                ss += __shfl_xor(ss, m, 64);
            }
            float mean = s * (1.0f / 64.0f);
            float var  = ss * (1.0f / 64.0f) - mean * mean;
            float rstd = rsqrtf(var + EPS);
#pragma unroll
            for (int j = 0; j < 4; ++j) c[j] = (c[j] - mean) * rstd;
        }
        size_t row = (size_t)(m0 + ty * 4 + i);
        *(float4*)&C[row * N + n0 + tx * 4] = make_float4(c[0], c[1], c[2], c[3]);
        if (ZP) {
            // token = row*8 + n0/64 (BN=64 spans exactly one token), dims tx*4..+3
            u16 hs[4] __attribute__((aligned(8)));
            u16 ls[4] __attribute__((aligned(8)));
            split2(c[0], hs[0], ls[0]); split2(c[1], hs[1], ls[1]);
            split2(c[2], hs[2], ls[2]); split2(c[3], hs[3], ls[3]);
            size_t tokoff = ((size_t)row * 8 + (n0 >> 6)) * CDIM + tx * 4;
            *(uint2*)&zph[tokoff] = *(const uint2*)hs;
            *(uint2*)&zpl[tokoff] = *(const uint2*)ls;
        }
    }
}

// ---------------------------------------------------------------------------
// DECODER GEMM2: split-bf16 MFMA GEMM (3-pass Markidis), pre-split A planes.
// Block 256 thr = 4 waves (2Mx2N), BM=128, BN=128, BK=32. [proven R2/R3]
// ---------------------------------------------------------------------------
template<int BM>
__launch_bounds__(256, 2)
__global__ void gemm_split(const u16* __restrict__ Ahi, const u16* __restrict__ Alo,
                           const u16* __restrict__ Bhi, const u16* __restrict__ Blo,
                           const float* __restrict__ bias,
                           float* __restrict__ Of,
                           int M, int N, int K)
{
    constexpr int WM  = BM / 2;
    constexpr int MI  = WM / 16;
    constexpr int AIT = BM / 32;

    __shared__ uint4 As[2][BM * 4];
    __shared__ uint4 Bs[2][128 * 4];

    const int tid = threadIdx.x;
    const int wid = tid >> 6, l = tid & 63, ln = l & 15, kg = l >> 4;
    const int mw = wid >> 1, nw = wid & 1;
    const int m0 = blockIdx.x * BM, n0 = blockIdx.y * 128;
    const int swz = (ln >> 1) & 3;

    f32x4 acc[MI][4];
#pragma unroll
    for (int i = 0; i < MI; ++i)
#pragma unroll
        for (int j = 0; j < 4; ++j) acc[i][j] = (f32x4){0.f, 0.f, 0.f, 0.f};

    uint4 ra[AIT];
    uint4 rb[4];

    auto gload = [&](int k0){
#pragma unroll
        for (int h = 0; h < AIT; ++h){
            int idx = tid + 256 * h; int r = idx >> 3, pl = (idx >> 2) & 1, c = idx & 3;
            const u16* p = (pl ? Alo : Ahi) + (size_t)(m0 + r) * K + k0 + c * 8;
            ra[h] = *(const uint4*)p;
        }
#pragma unroll
        for (int h = 0; h < 4; ++h){
            int idx = tid + 256 * h; int r = idx >> 3, pl = (idx >> 2) & 1, c = idx & 3;
            const u16* p = (pl ? Blo : Bhi) + (size_t)(n0 + r) * K + k0 + c * 8;
            rb[h] = *(const uint4*)p;
        }
    };
    auto lstore = [&](){
#pragma unroll
        for (int h = 0; h < AIT; ++h){
            int idx = tid + 256 * h; int r = idx >> 3, pl = (idx >> 2) & 1, c = idx & 3;
            As[pl][r * 4 + (c ^ ((r >> 1) & 3))] = ra[h];
        }
#pragma unroll
        for (int h = 0; h < 4; ++h){
            int idx = tid + 256 * h; int r = idx >> 3, pl = (idx >> 2) & 1, c = idx & 3;
            Bs[pl][r * 4 + (c ^ ((r >> 1) & 3))] = rb[h];
        }
    };

    gload(0);
    for (int k0 = 0; k0 < K; k0 += 32){
        if (k0) __syncthreads();
        lstore();
        __syncthreads();
        if (k0 + 32 < K) gload(k0 + 32);

        bf16x8 af[MI][2], bfr[4][2];
#pragma unroll
        for (int mi = 0; mi < MI; ++mi){
            int r = mw * WM + mi * 16 + ln;
            af[mi][0] = *(bf16x8*)&As[0][r * 4 + (kg ^ swz)];
            af[mi][1] = *(bf16x8*)&As[1][r * 4 + (kg ^ swz)];
        }
#pragma unroll
        for (int ni = 0; ni < 4; ++ni){
            int r = nw * 64 + ni * 16 + ln;
            bfr[ni][0] = *(bf16x8*)&Bs[0][r * 4 + (kg ^ swz)];
            bfr[ni][1] = *(bf16x8*)&Bs[1][r * 4 + (kg ^ swz)];
        }
#pragma unroll
        for (int mi = 0; mi < MI; ++mi)
#pragma unroll
            for (int ni = 0; ni < 4; ++ni){
                acc[mi][ni] = MFMA16(af[mi][0], bfr[ni][0], acc[mi][ni]);  // hi*hi
                acc[mi][ni] = MFMA16(af[mi][0], bfr[ni][1], acc[mi][ni]);  // hi*lo
                acc[mi][ni] = MFMA16(af[mi][1], bfr[ni][0], acc[mi][ni]);  // lo*hi
            }
    }

    float bv[4];
#pragma unroll
    for (int ni = 0; ni < 4; ++ni) bv[ni] = bias[n0 + nw * 64 + ni * 16 + ln];

#pragma unroll
    for (int mi = 0; mi < MI; ++mi){
#pragma unroll
        for (int r = 0; r < 4; ++r){
            size_t row = (size_t)(m0 + mw * WM + mi * 16 + kg * 4 + r);
#pragma unroll
            for (int ni = 0; ni < 4; ++ni){
                int col = n0 + nw * 64 + ni * 16 + ln;
                Of[row * N + col] = acc[mi][ni][r] + bv[ni];
            }
        }
    }
}

// ---------------------------------------------------------------------------
// VQ mega: 256 blocks x 1024 thr (16 waves, 1 block/CU, 4 waves/SIMD).
// Whole codebook hi/lo planes staged in LDS ONCE (128KB, one barrier), then
// each wave independently: 32 tokens (2 m-frags) x all 512 codes, 384 MFMAs,
// ZERO barriers. a-frags from pre-split z planes (global, L3-hot). b-frags via
// swizzled ds_read_b128 (slot = c ^ (code&7), measured 0 bank conflicts).
// Per-lane best/2nd (strict <, ascending codes) -> 16-lane butterfly ->
// wave-local margin rescue (exact fp32) -> zq/idx writes + P-table h-gather.
// ---------------------------------------------------------------------------
__launch_bounds__(1024, 4)
__global__ void vq_mega(const u16* __restrict__ Zh, const u16* __restrict__ Zl,
                        const float* __restrict__ zf32,
                        const u16* __restrict__ Chi, const u16* __restrict__ Clo,
                        const float* __restrict__ cbf, const float* __restrict__ c2,
                        const float* __restrict__ Ptab, const float* __restrict__ db1,
                        float* __restrict__ zq_o, float* __restrict__ idx_o,
                        u16* __restrict__ h_h, u16* __restrict__ h_l)
{
    __shared__ uint4 CB[2][NCODES][8];   // 128KB: [plane][code][slot], slot = c ^ (code&7)
    __shared__ float c2s[NCODES];        // 2KB
    __shared__ int   fIw[16][32];        // per-wave final indices, 2KB

    const int tid = threadIdx.x;
    const int wid = tid >> 6, l = tid & 63, ln = l & 15, kg = l >> 4;
    const int tile = blockIdx.x * 16 + wid;     // 0..4095
    const int tok0 = tile * 32;

    // stage codebook planes -> regs (in flight while a-frags load)
    uint4 rcb[8];
#pragma unroll
    for (int h = 0; h < 8; ++h){
        int idx = tid + 1024 * h;        // 0..8191 16B-chunks
        int pl = idx >> 12, r = (idx >> 3) & 511, c = idx & 7;
        rcb[h] = *(const uint4*)((pl ? Clo : Chi) + (size_t)r * CDIM + c * 8);
    }

    // a-frags: 2 m-frags of 16 tokens each, from pre-split z planes
    bf16x8 a[2][2][2];   // [mi][ks][plane]
#pragma unroll
    for (int mi = 0; mi < 2; ++mi){
        const u16* ph = Zh + (size_t)(tok0 + mi * 16 + ln) * CDIM + kg * 8;
        const u16* pl2 = Zl + (size_t)(tok0 + mi * 16 + ln) * CDIM + kg * 8;
        a[mi][0][0] = *(const bf16x8*)ph;
        a[mi][1][0] = *(const bf16x8*)(ph + 32);
        a[mi][0][1] = *(const bf16x8*)pl2;
        a[mi][1][1] = *(const bf16x8*)(pl2 + 32);
    }
    if (tid < NCODES) c2s[tid] = c2[tid];
#pragma unroll
    for (int h = 0; h < 8; ++h){
        int idx = tid + 1024 * h;
        int pl = idx >> 12, r = (idx >> 3) & 511, c = idx & 7;
        CB[pl][r][c ^ (r & 7)] = rcb[h];
    }
    __syncthreads();     // the ONLY block barrier

    float b1[2][4], b2[2][4]; int i1[2][4];
#pragma unroll
    for (int mi = 0; mi < 2; ++mi)
#pragma unroll
        for (int r = 0; r < 4; ++r){ b1[mi][r] = 3.4e38f; b2[mi][r] = 3.4e38f; i1[mi][r] = 0; }

#pragma unroll 4
    for (int ni = 0; ni < 32; ++ni){
        int r = ni * 16 + ln, sw = r & 7;
        bf16x8 b0h = *(const bf16x8*)&CB[0][r][kg ^ sw];
        bf16x8 b1h = *(const bf16x8*)&CB[0][r][(4 + kg) ^ sw];
        bf16x8 b0l = *(const bf16x8*)&CB[1][r][kg ^ sw];
        bf16x8 b1l = *(const bf16x8*)&CB[1][r][(4 + kg) ^ sw];

        f32x4 t0 = (f32x4){0.f,0.f,0.f,0.f}, t1 = (f32x4){0.f,0.f,0.f,0.f};
        t0 = MFMA16(a[0][0][0], b0h, t0);  t1 = MFMA16(a[1][0][0], b0h, t1);
        t0 = MFMA16(a[0][0][0], b0l, t0);  t1 = MFMA16(a[1][0][0], b0l, t1);
        t0 = MFMA16(a[0][0][1], b0h, t0);  t1 = MFMA16(a[1][0][1], b0h, t1);
        t0 = MFMA16(a[0][1][0], b1h, t0);  t1 = MFMA16(a[1][1][0], b1h, t1);
        t0 = MFMA16(a[0][1][0], b1l, t0);  t1 = MFMA16(a[1][1][0], b1l, t1);
        t0 = MFMA16(a[0][1][1], b1h, t0);  t1 = MFMA16(a[1][1][1], b1h, t1);

        int code = ni * 16 + ln;
        float cv = c2s[code];
#pragma unroll
        for (int r4 = 0; r4 < 4; ++r4){
            float d = fmaf(-2.f, t0[r4], cv);
            if (d < b1[0][r4]) { b2[0][r4] = b1[0][r4]; b1[0][r4] = d; i1[0][r4] = code; }
            else if (d < b2[0][r4]) b2[0][r4] = d;
            float e = fmaf(-2.f, t1[r4], cv);
            if (e < b1[1][r4]) { b2[1][r4] = b1[1][r4]; b1[1][r4] = e; i1[1][r4] = code; }
            else if (e < b2[1][r4]) b2[1][r4] = e;
        }
    }

    // 16-lane butterfly per token (tie -> lower idx); margin mask collection
    u32 rmask = 0;
#pragma unroll
    for (int mi = 0; mi < 2; ++mi)
#pragma unroll
        for (int r = 0; r < 4; ++r){
            float v1 = b1[mi][r], v2 = b2[mi][r]; int ii = i1[mi][r];
#pragma unroll
            for (int mk = 1; mk <= 8; mk <<= 1){
                float o1 = __shfl_xor(v1, mk, 64), o2 = __shfl_xor(v2, mk, 64);
                int   oi = __shfl_xor(ii, mk, 64);
                float n2 = fminf(fmaxf(v1, o1), fminf(v2, o2));
                if (o1 < v1 || (o1 == v1 && oi < ii)){ v1 = o1; ii = oi; }
                v2 = n2;
            }
            if (ln == 0) fIw[wid][mi * 16 + kg * 4 + r] = ii;
            if (v2 - v1 < MARGIN) rmask |= 1u << (mi * 16 + kg * 4 + r);
        }
    rmask |= __shfl_xor(rmask, 16, 64);
    rmask |= __shfl_xor(rmask, 32, 64);

    // wave-local exact fp32 rescue (rare); lane handles 8 ascending codes
    while (rmask){
        int tk = __builtin_ctz(rmask); rmask &= rmask - 1;
        const float* zr = zf32 + (size_t)(tok0 + tk) * CDIM;
        float best = 3.4e38f; int bi = 0;
#pragma unroll
        for (int j = 0; j < 8; ++j){
            int c = l * 8 + j;
            const float* cp = cbf + (size_t)c * CDIM;
            float d0 = 0.f, d1 = 0.f, d2 = 0.f, d3 = 0.f;
#pragma unroll
            for (int d4 = 0; d4 < 16; ++d4){
                float4 zz = *(const float4*)(zr + d4 * 4);   // same addr all lanes (L1)
                float4 cc = *(const float4*)(cp + d4 * 4);
                d0 = fmaf(zz.x, cc.x, d0); d1 = fmaf(zz.y, cc.y, d1);
                d2 = fmaf(zz.z, cc.z, d2); d3 = fmaf(zz.w, cc.w, d3);
            }
            float d = fmaf(-2.f, (d0 + d1) + (d2 + d3), c2s[c]);
            if (d < best){ best = d; bi = c; }
        }
#pragma unroll
        for (int mk = 1; mk < 64; mk <<= 1){
            float o = __shfl_xor(best, mk, 64); int oi = __shfl_xor(bi, mk, 64);
            if (o < best || (o == best && oi < bi)){ best = o; bi = oi; }
        }
        if (l == 0) fIw[wid][tk] = bi;
    }
    // wave-internal LDS RAW fence (no block barrier needed)
    asm volatile("s_waitcnt lgkmcnt(0)" ::: "memory");
    __builtin_amdgcn_sched_barrier(0);

    // idx output (32 tokens)
    if (l < 32) idx_o[tok0 + l] = (float)fIw[wid][l];

    // zq output: lane pair per token, 32 dims each (exact fp32 codebook gather)
    {
        int tk = l >> 1, half = l & 1;
        int ii = fIw[wid][tk];
        const float* cf = cbf + (size_t)ii * CDIM + half * 32;
        float* zo = zq_o + (size_t)(tok0 + tk) * CDIM + half * 32;
#pragma unroll
        for (int q = 0; q < 8; ++q)
            *(float4*)(zo + q * 4) = *(const float4*)(cf + q * 4);
    }

    // fused decoder GEMM1: h = relu(b1 + sum_t P[idx_t][t][:]) for 4 samples
    {
        int sl = l >> 4, jj = (l & 15) * 8;           // sample-in-wave, col base
        int samp = tile * 4 + sl;
        float4 h0 = *(const float4*)&db1[jj];
        float4 h1 = *(const float4*)&db1[jj + 4];
#pragma unroll
        for (int t = 0; t < 8; ++t){
            int c = fIw[wid][sl * 8 + t];
            const float* pp = Ptab + ((size_t)c * 8 + t) * HID + jj;
            float4 p0 = *(const float4*)pp, p1 = *(const float4*)(pp + 4);
            h0.x += p0.x; h0.y += p0.y; h0.z += p0.z; h0.w += p0.w;
            h1.x += p1.x; h1.y += p1.y; h1.z += p1.z; h1.w += p1.w;
        }
        float hv[8] = {fmaxf(h0.x,0.f), fmaxf(h0.y,0.f), fmaxf(h0.z,0.f), fmaxf(h0.w,0.f),
                       fmaxf(h1.x,0.f), fmaxf(h1.y,0.f), fmaxf(h1.z,0.f), fmaxf(h1.w,0.f)};
        u16 hh[8] __attribute__((aligned(16)));
        u16 ll[8] __attribute__((aligned(16)));
#pragma unroll
        for (int q = 0; q < 8; ++q) split2(hv[q], hh[q], ll[q]);
        size_t hrow = (size_t)samp * HID + jj;
        *(uint4*)&h_h[hrow] = *(const uint4*)hh;
        *(uint4*)&h_l[hrow] = *(const uint4*)ll;
    }
}

// ---------------------------------------------------------------------------
extern "C" void kernel_launch(void* const* d_in, const int* in_sizes, int n_in,
                              void* d_out, int out_size, void* d_ws, size_t ws_size,
                              hipStream_t stream) {
    const float* x      = (const float*)d_in[0];
    const float* enc_w1 = (const float*)d_in[1];
    const float* enc_b1 = (const float*)d_in[2];
    const float* enc_w2 = (const float*)d_in[3];
    const float* enc_b2 = (const float*)d_in[4];
    const float* cbk    = (const float*)d_in[5];
    const float* dec_w1 = (const float*)d_in[6];
    const float* dec_b1 = (const float*)d_in[7];
    const float* dec_w2 = (const float*)d_in[8];
    const float* dec_b2 = (const float*)d_in[9];

    // outputs, all float32, concatenated flat: recon | z_q | indices
    float* out     = (float*)d_out;
    float* recon_o = out;
    float* zq_o    = out + (size_t)B_ * TD;
    float* idx_o   = out + 2 * (size_t)B_ * TD;

    // workspace carve-up
    float* zbuf  = (float*)d_ws;                       // [B,512] fp32 z (post-LN)
    float* hbuf  = zbuf + (size_t)B_ * TD;             // [B,128] fp32 enc hidden / dec h planes
    float* c2buf = hbuf + (size_t)B_ * HID;            // 512 fp32
    float* Ptab  = c2buf + 512;                        // 512*8*128 fp32 = 2 MB
    u16* w = (u16*)(Ptab + (size_t)NCODES * NTOK * HID);
    u16* d2t_h = w; w += 65536;   u16* d2t_l = w; w += 65536;   // dec_w2^T [512][128]
    u16* cb_h  = w; w += 32768;   u16* cb_l  = w; w += 32768;   // codebook [512][64]
    u16* z_h   = w; w += (size_t)B_ * NTOK * CDIM;              // z planes [131072][64]
    u16* z_l   = w; w += (size_t)B_ * NTOK * CDIM;
    // decoder hidden planes alias hbuf (hbuf dead after encoder GEMM2)
    u16* h_h = (u16*)hbuf;
    u16* h_l = h_h + (size_t)B_ * HID;

    // ---- prep ----
    hipLaunchKernelGGL(tsplit_kernel, dim3(256), dim3(256), 0, stream, dec_w2, d2t_h, d2t_l, TD, 7);
    hipLaunchKernelGGL(csplit_kernel, dim3(128), dim3(256), 0, stream, cbk, cb_h, cb_l);
    hipLaunchKernelGGL(c2_kernel, dim3(NCODES), dim3(64), 0, stream, cbk, c2buf);
    hipLaunchKernelGGL(pprep_kernel, dim3(NCODES, NTOK), dim3(HID), 0, stream, cbk, dec_w1, Ptab);

    // ---- encoder GEMM1 + ReLU (fp32 VALU): x[16384,512] @ w1 -> hbuf ----
    hipLaunchKernelGGL((gemm_kernel<true, false, false>), dim3(B_ / 64, HID / 64), dim3(256), 0,
                       stream, x, enc_w1, enc_b1, hbuf, (u16*)nullptr, (u16*)nullptr,
                       B_, HID, TD);

    // ---- encoder GEMM2 + LN (fp32 VALU): hbuf @ w2 -> zbuf (+ z planes) ----
    hipLaunchKernelGGL((gemm_kernel<false, true, true>), dim3(B_ / 64, LAT / 64), dim3(256), 0,
                       stream, hbuf, enc_w2, enc_b2, zbuf, z_h, z_l,
                       B_, LAT, HID);

    // ---- VQ mega (barrier-free MFMA argmin + rescue + zq/idx + h planes) ----
    hipLaunchKernelGGL(vq_mega, dim3(256), dim3(1024), 0, stream,
                       z_h, z_l, zbuf, cb_h, cb_l, cbk, c2buf, Ptab, dec_b1,
                       zq_o, idx_o, h_h, h_l);

    // ---- decoder GEMM2 (MFMA): h planes @ dw2 -> recon fp32 ----
    hipLaunchKernelGGL((gemm_split<128>), dim3(B_ / 128, TD / 128), dim3(256), 0,
                       stream, h_h, h_l, d2t_h, d2t_l, dec_b2, recon_o, B_, TD, HID);
}